// Round 8
// baseline (116.997 us; speedup 1.0000x reference)
//
#include <hip/hip_runtime.h>

#define N_DIM 4096
#define SCALE 7.3890560989306495f   // e^2 (T = 2.0)

// 2 waves per row, 4-wave (256-thread) blocks => 2 rows/block, 2048 blocks,
// 8192 waves => 8 waves/SIMD occupancy (needs <=64 VGPR: launch_bounds(256,8)).
// Labels staged once per block into LDS (16KB); pass 1 then issues ONLY the 8
// logits float4 loads per wave. Cross-half combine of S/Smask/Emax via LDS.
// Rare-correction rescan re-loads hit groups from L1 (bit-identical exp).
__global__ __launch_bounds__(256, 8) void minfonce_kernel(
    const float* __restrict__ logits,
    const int*   __restrict__ labels,
    float*       __restrict__ out)
{
    const int tid  = threadIdx.x;
    const int lane = tid & 63;
    const int wv   = tid >> 6;          // 0..3
    const int half = wv & 1;            // which half of the row
    const int row  = (blockIdx.x << 1) + (wv >> 1);
    const int g0   = half << 3;         // first float4-group of this half

    __shared__ int4  slab[N_DIM / 4];   // 16 KB: all 4096 labels
    __shared__ float sS[4], sX[4], sM[4], sA[4];

    // ---- stage labels: 256 threads x 4 int4 (coalesced) ----
    const int4* lp = reinterpret_cast<const int4*>(labels);
#pragma unroll
    for (int j = 0; j < 4; ++j) slab[tid + 256 * j] = lp[tid + 256 * j];
    __syncthreads();

    const float4* rp = reinterpret_cast<const float4*>(logits + (size_t)row * N_DIM);
    const int     li = reinterpret_cast<const int*>(slab)[row];

    // ---- pass 1: stream 8 float4 groups, accumulate S / Smask / per-group max ----
    float m8[8];
    float s_all = 0.f, s_mask = 0.f;
#pragma unroll
    for (int g = 0; g < 8; ++g) {
        const float4 t  = rp[lane + 64 * (g0 + g)];
        const int4   lb = slab[lane + 64 * (g0 + g)];
        const float ex = __expf(SCALE * t.x);
        const float ey = __expf(SCALE * t.y);
        const float ez = __expf(SCALE * t.z);
        const float ew = __expf(SCALE * t.w);
        s_all  += (ex + ey) + (ez + ew);
        s_mask += ((lb.x != li ? ex : 0.f) + (lb.y != li ? ey : 0.f))
                + ((lb.z != li ? ez : 0.f) + (lb.w != li ? ew : 0.f));
        m8[g] = fmaxf(fmaxf(ex, ey), fmaxf(ez, ew));
    }
    float emax = m8[0];
#pragma unroll
    for (int g = 1; g < 8; ++g) emax = fmaxf(emax, m8[g]);

    // ---- intra-wave butterfly ----
#pragma unroll
    for (int off = 1; off < 64; off <<= 1) {
        s_all  += __shfl_xor(s_all, off);
        s_mask += __shfl_xor(s_mask, off);
        emax    = fmaxf(emax, __shfl_xor(emax, off));
    }
    if (lane == 0) { sS[wv] = s_all; sX[wv] = s_mask; sM[wv] = emax; }
    __syncthreads();

    // ---- combine the row's two half-wave partials ----
    const int  w0    = wv & ~1;
    const float S     = sS[w0] + sS[w0 | 1];
    const float Smask = sX[w0] + sX[w0 | 1];
    const float Emax  = fmaxf(sM[w0], sM[w0 | 1]);
    const float invS  = 1.0f / S;
    const float tau   = 1e-3f * S;                 // correction threshold (p > 1e-3)
    // 1 - p_max = (S - Emax)/S, cancellation-free; clamp guards S==Emax rounding.
    const float qmax  = fmaxf(S - Emax, S * 1e-12f) * invS;

    // ---- rare-correction scan over this half's 8 groups ----
    float acc = 0.f;
#pragma unroll
    for (int g = 0; g < 8; ++g) {
        if (m8[g] > tau) {                         // rare (~0-4 groups per half-wave)
            const float4 t  = rp[lane + 64 * (g0 + g)];   // L1 hit
            const int4   lb = slab[lane + 64 * (g0 + g)];
            { const float ev = __expf(SCALE * t.x);
              if (ev > tau && lb.x != li) {
                  const float p = ev * invS;
                  const float q = (ev == Emax) ? qmax : (1.0f - p);
                  acc += __logf(q) + p; } }        // exact log1p(-p), minus bulk's -p
            { const float ev = __expf(SCALE * t.y);
              if (ev > tau && lb.y != li) {
                  const float p = ev * invS;
                  const float q = (ev == Emax) ? qmax : (1.0f - p);
                  acc += __logf(q) + p; } }
            { const float ev = __expf(SCALE * t.z);
              if (ev > tau && lb.z != li) {
                  const float p = ev * invS;
                  const float q = (ev == Emax) ? qmax : (1.0f - p);
                  acc += __logf(q) + p; } }
            { const float ev = __expf(SCALE * t.w);
              if (ev > tau && lb.w != li) {
                  const float p = ev * invS;
                  const float q = (ev == Emax) ? qmax : (1.0f - p);
                  acc += __logf(q) + p; } }
        }
    }

    // ---- per-row single-lane terms: diagonal + bulk -Smask/S (half 0 only) ----
    if (half == 0 && lane == 0)
        acc += (SCALE * logits[(size_t)row * N_DIM + row] - __logf(S))
             - Smask * invS;

#pragma unroll
    for (int off = 1; off < 64; off <<= 1)
        acc += __shfl_xor(acc, off);

    if (lane == 0) sA[wv] = acc;
    __syncthreads();
    if (tid == 0) {
        const float total = (sA[0] + sA[1]) + (sA[2] + sA[3]);
        atomicAdd(out, total * (1.0f / N_DIM));
    }
}

extern "C" void kernel_launch(void* const* d_in, const int* in_sizes, int n_in,
                              void* d_out, int out_size, void* d_ws, size_t ws_size,
                              hipStream_t stream) {
    const float* logits = (const float*)d_in[0];
    const int*   labels = (const int*)d_in[1];
    float*       out    = (float*)d_out;

    // d_out is poisoned (0xAA) before every timed launch — zero it ourselves.
    hipMemsetAsync(out, 0, sizeof(float), stream);
    minfonce_kernel<<<N_DIM / 2, 256, 0, stream>>>(logits, labels, out);
}

// Round 9
// 115.157 us; speedup vs baseline: 1.0160x; 1.0160x over previous
//
#include <hip/hip_runtime.h>

#define N_DIM 4096
#define SCALE 7.3890560989306495f   // e^2 (T = 2.0)

// 2 waves per row, 256-thread blocks (2 rows/block), 2048 blocks.
// launch_bounds(256,4): VGPR cap 128 -> all 16 loads (8 logits float4 +
// 8 labels int4) issued up front and kept in registers; sched_barrier(0)
// pins the load cluster so compute overlaps the in-flight loads via counted
// vmcnt waits. No LDS staging, no mid-kernel barrier (only the final reduce).
// Rare-correction rescan reads the register copies (zero reloads).
__global__ __launch_bounds__(256, 4) void minfonce_kernel(
    const float* __restrict__ logits,
    const int*   __restrict__ labels,
    float*       __restrict__ out)
{
    const int tid  = threadIdx.x;
    const int lane = tid & 63;
    const int wv   = tid >> 6;                    // 0..3
    const int half = wv & 1;                      // which half of the row
    const int row  = (blockIdx.x << 1) + (wv >> 1);

    __shared__ float sS[4], sX[4], sM[4], sA[4];

    const float4* rp = reinterpret_cast<const float4*>(logits + (size_t)row * N_DIM);
    const int4*   lp = reinterpret_cast<const int4*>(labels);
    const int     li = labels[row];               // uniform -> s_load, L2 hit
    const int     i0 = lane + (half << 9);        // lane + 512*half

    // ---- issue ALL loads up front: 8x float4 logits + 8x int4 labels ----
    const float4 u0 = rp[i0 +   0]; const int4 b0 = lp[i0 +   0];
    const float4 u1 = rp[i0 +  64]; const int4 b1 = lp[i0 +  64];
    const float4 u2 = rp[i0 + 128]; const int4 b2 = lp[i0 + 128];
    const float4 u3 = rp[i0 + 192]; const int4 b3 = lp[i0 + 192];
    const float4 u4 = rp[i0 + 256]; const int4 b4 = lp[i0 + 256];
    const float4 u5 = rp[i0 + 320]; const int4 b5 = lp[i0 + 320];
    const float4 u6 = rp[i0 + 384]; const int4 b6 = lp[i0 + 384];
    const float4 u7 = rp[i0 + 448]; const int4 b7 = lp[i0 + 448];
    __builtin_amdgcn_sched_barrier(0);            // keep the load cluster here

    // ---- pass 1: consume in issue order (counted vmcnt overlap) ----
    float m8[8];
    float s_all = 0.f, s_mask = 0.f;
#define ACCG(G, T, B) do {                                             \
        const float ex = __expf(SCALE * T.x);                          \
        const float ey = __expf(SCALE * T.y);                          \
        const float ez = __expf(SCALE * T.z);                          \
        const float ew = __expf(SCALE * T.w);                          \
        s_all  += (ex + ey) + (ez + ew);                               \
        s_mask += ((B.x != li ? ex : 0.f) + (B.y != li ? ey : 0.f))    \
                + ((B.z != li ? ez : 0.f) + (B.w != li ? ew : 0.f));   \
        m8[G] = fmaxf(fmaxf(ex, ey), fmaxf(ez, ew));                   \
    } while (0)
    ACCG(0, u0, b0); ACCG(1, u1, b1); ACCG(2, u2, b2); ACCG(3, u3, b3);
    ACCG(4, u4, b4); ACCG(5, u5, b5); ACCG(6, u6, b6); ACCG(7, u7, b7);
#undef ACCG

    float emax = m8[0];
#pragma unroll
    for (int g = 1; g < 8; ++g) emax = fmaxf(emax, m8[g]);

    // ---- intra-wave butterfly ----
#pragma unroll
    for (int off = 1; off < 64; off <<= 1) {
        s_all  += __shfl_xor(s_all, off);
        s_mask += __shfl_xor(s_mask, off);
        emax    = fmaxf(emax, __shfl_xor(emax, off));
    }
    if (lane == 0) { sS[wv] = s_all; sX[wv] = s_mask; sM[wv] = emax; }
    __syncthreads();

    // ---- combine the row's two half-wave partials ----
    const int   w0    = wv & ~1;
    const float S     = sS[w0] + sS[w0 | 1];
    const float Smask = sX[w0] + sX[w0 | 1];
    const float Emax  = fmaxf(sM[w0], sM[w0 | 1]);
    const float invS  = 1.0f / S;
    const float tau   = 1e-3f * S;                // correction threshold (p > 1e-3)
    // 1 - p_max = (S - Emax)/S, cancellation-free; clamp guards S==Emax rounding.
    const float qmax  = fmaxf(S - Emax, S * 1e-12f) * invS;

    // ---- rare-correction scan straight from registers ----
    float acc = 0.f;
#define FIX1(X, L) {                                                   \
        const float ev = __expf(SCALE * (X));                          \
        if (ev > tau && (L) != li) {                                   \
            const float p = ev * invS;                                 \
            const float q = (ev == Emax) ? qmax : (1.0f - p);          \
            acc += __logf(q) + p; } }
#define FIXG(G, T, B) if (m8[G] > tau) {                               \
        FIX1(T.x, B.x) FIX1(T.y, B.y) FIX1(T.z, B.z) FIX1(T.w, B.w) }
    FIXG(0, u0, b0); FIXG(1, u1, b1); FIXG(2, u2, b2); FIXG(3, u3, b3);
    FIXG(4, u4, b4); FIXG(5, u5, b5); FIXG(6, u6, b6); FIXG(7, u7, b7);
#undef FIXG
#undef FIX1

    // ---- per-row single-lane terms: diagonal + bulk -Smask/S (half 0 only) ----
    if (half == 0 && lane == 0)
        acc += (SCALE * logits[(size_t)row * N_DIM + row] - __logf(S))
             - Smask * invS;

#pragma unroll
    for (int off = 1; off < 64; off <<= 1)
        acc += __shfl_xor(acc, off);

    if (lane == 0) sA[wv] = acc;
    __syncthreads();
    if (tid == 0) {
        const float total = (sA[0] + sA[1]) + (sA[2] + sA[3]);
        atomicAdd(out, total * (1.0f / N_DIM));
    }
}

extern "C" void kernel_launch(void* const* d_in, const int* in_sizes, int n_in,
                              void* d_out, int out_size, void* d_ws, size_t ws_size,
                              hipStream_t stream) {
    const float* logits = (const float*)d_in[0];
    const int*   labels = (const int*)d_in[1];
    float*       out    = (float*)d_out;

    // d_out is poisoned (0xAA) before every timed launch — zero it ourselves.
    hipMemsetAsync(out, 0, sizeof(float), stream);
    minfonce_kernel<<<N_DIM / 2, 256, 0, stream>>>(logits, labels, out);
}

// Round 10
// 96.838 us; speedup vs baseline: 1.2082x; 1.1892x over previous
//
#include <hip/hip_runtime.h>

#define N_DIM 4096
#define SCALE 7.3890560989306495f   // e^2 (T = 2.0)

// K1: one full row per wave. 512 blocks x 512 threads = 4096 waves = 16/CU,
// single generation (all blocks resident at once, no re-dispatch).
// Labels staged once into LDS (16KB, lgkmcnt pipe). All 16 logits float4
// loads + diagonal issued as an up-front cluster (counted-vmcnt overlap),
// consumed from registers; rare-correction rescan also from registers.
// NO same-address atomic: per-block partial -> ws[blockIdx]; K2 reduces.
__global__ __launch_bounds__(512, 4) void minfonce_rows(
    const float* __restrict__ logits,
    const int*   __restrict__ labels,
    float*       __restrict__ ws)
{
    const int tid  = threadIdx.x;
    const int lane = tid & 63;
    const int wv   = tid >> 6;                    // 0..7
    const int row  = (blockIdx.x << 3) + wv;

    __shared__ int4  slab[N_DIM / 4];             // 16 KB: all 4096 labels
    __shared__ float sacc[8];

    // ---- stage labels once (512 threads x 2 int4, coalesced) ----
    const int4* lp = reinterpret_cast<const int4*>(labels);
    slab[tid]       = lp[tid];
    slab[tid + 512] = lp[tid + 512];
    const int li = labels[row];
    __syncthreads();                              // only pre-compute barrier

    const float4* rp = reinterpret_cast<const float4*>(logits + (size_t)row * N_DIM);

    // ---- issue the whole row as one load cluster (16 x float4 + diag) ----
    const float4 u0  = rp[lane +   0];
    const float4 u1  = rp[lane +  64];
    const float4 u2  = rp[lane + 128];
    const float4 u3  = rp[lane + 192];
    const float4 u4  = rp[lane + 256];
    const float4 u5  = rp[lane + 320];
    const float4 u6  = rp[lane + 384];
    const float4 u7  = rp[lane + 448];
    const float4 u8  = rp[lane + 512];
    const float4 u9  = rp[lane + 576];
    const float4 u10 = rp[lane + 640];
    const float4 u11 = rp[lane + 704];
    const float4 u12 = rp[lane + 768];
    const float4 u13 = rp[lane + 832];
    const float4 u14 = rp[lane + 896];
    const float4 u15 = rp[lane + 960];
    const float  dv  = logits[(size_t)row * N_DIM + row];  // same-addr bcast
    __builtin_amdgcn_sched_barrier(0);            // pin the cluster here

    // ---- consume in issue order ----
    float m16[16];
    float s_all = 0.f, s_mask = 0.f;
#define ACCG(G, U) do {                                                \
        const int4  lb = slab[lane + 64 * (G)];                        \
        const float ex = __expf(SCALE * U.x);                          \
        const float ey = __expf(SCALE * U.y);                          \
        const float ez = __expf(SCALE * U.z);                          \
        const float ew = __expf(SCALE * U.w);                          \
        s_all  += (ex + ey) + (ez + ew);                               \
        s_mask += ((lb.x != li ? ex : 0.f) + (lb.y != li ? ey : 0.f))  \
                + ((lb.z != li ? ez : 0.f) + (lb.w != li ? ew : 0.f)); \
        m16[G] = fmaxf(fmaxf(ex, ey), fmaxf(ez, ew));                  \
    } while (0)
    ACCG(0, u0);   ACCG(1, u1);   ACCG(2, u2);   ACCG(3, u3);
    ACCG(4, u4);   ACCG(5, u5);   ACCG(6, u6);   ACCG(7, u7);
    ACCG(8, u8);   ACCG(9, u9);   ACCG(10, u10); ACCG(11, u11);
    ACCG(12, u12); ACCG(13, u13); ACCG(14, u14); ACCG(15, u15);
#undef ACCG

    float emax = m16[0];
#pragma unroll
    for (int g = 1; g < 16; ++g) emax = fmaxf(emax, m16[g]);

    // ---- intra-wave butterfly: full-row totals, no cross-wave combine ----
#pragma unroll
    for (int off = 1; off < 64; off <<= 1) {
        s_all  += __shfl_xor(s_all, off);
        s_mask += __shfl_xor(s_mask, off);
        emax    = fmaxf(emax, __shfl_xor(emax, off));
    }
    const float S    = s_all;
    const float invS = 1.0f / S;
    const float tau  = 1e-3f * S;                 // correction threshold (p > 1e-3)
    // 1 - p_max = (S - Emax)/S, cancellation-free; clamp guards S==Emax rounding.
    const float qmax = fmaxf(S - emax, S * 1e-12f) * invS;

    // ---- rare-correction scan straight from registers ----
    float acc = 0.f;
#define FIX1(X, L) {                                                   \
        const float ev = __expf(SCALE * (X));                          \
        if (ev > tau && (L) != li) {                                   \
            const float p = ev * invS;                                 \
            const float q = (ev == emax) ? qmax : (1.0f - p);          \
            acc += __logf(q) + p; } }
#define FIXG(G, U) if (m16[G] > tau) {                                 \
        const int4 lb = slab[lane + 64 * (G)];                         \
        FIX1(U.x, lb.x) FIX1(U.y, lb.y) FIX1(U.z, lb.z) FIX1(U.w, lb.w) }
    FIXG(0, u0);   FIXG(1, u1);   FIXG(2, u2);   FIXG(3, u3);
    FIXG(4, u4);   FIXG(5, u5);   FIXG(6, u6);   FIXG(7, u7);
    FIXG(8, u8);   FIXG(9, u9);   FIXG(10, u10); FIXG(11, u11);
    FIXG(12, u12); FIXG(13, u13); FIXG(14, u14); FIXG(15, u15);
#undef FIXG
#undef FIX1

    // ---- wave total; lane 0 adds diagonal + bulk -Smask/S ----
#pragma unroll
    for (int off = 1; off < 64; off <<= 1)
        acc += __shfl_xor(acc, off);
    if (lane == 0)
        sacc[wv] = acc + (SCALE * dv - __logf(S)) - s_mask * invS;
    __syncthreads();
    if (tid == 0) {
        const float total = ((sacc[0] + sacc[1]) + (sacc[2] + sacc[3]))
                          + ((sacc[4] + sacc[5]) + (sacc[6] + sacc[7]));
        ws[blockIdx.x] = total;                   // no atomic
    }
}

// K2: sum the 512 per-block partials, write the final scalar (overwrites
// poisoned d_out directly -- no memset needed).
__global__ __launch_bounds__(64) void minfonce_reduce(
    const float* __restrict__ ws,
    float*       __restrict__ out)
{
    const int lane = threadIdx.x;                 // one wave
    float a = 0.f;
#pragma unroll
    for (int i = 0; i < 8; ++i) a += ws[lane + 64 * i];
#pragma unroll
    for (int off = 1; off < 64; off <<= 1)
        a += __shfl_xor(a, off);
    if (lane == 0) out[0] = a * (1.0f / N_DIM);
}

extern "C" void kernel_launch(void* const* d_in, const int* in_sizes, int n_in,
                              void* d_out, int out_size, void* d_ws, size_t ws_size,
                              hipStream_t stream) {
    const float* logits = (const float*)d_in[0];
    const int*   labels = (const int*)d_in[1];
    float*       out    = (float*)d_out;
    float*       ws     = (float*)d_ws;

    minfonce_rows<<<N_DIM / 8, 512, 0, stream>>>(logits, labels, ws);
    minfonce_reduce<<<1, 64, 0, stream>>>(ws, out);
}

// Round 11
// 95.832 us; speedup vs baseline: 1.2209x; 1.0105x over previous
//
#include <hip/hip_runtime.h>

#define N_DIM 4096
#define SCALE 7.3890560989306495f   // e^2 (T = 2.0)

// K1: 2 waves per row, 512-thread blocks (8 waves = 4 rows/block),
// 1024 blocks = 8192 waves = 32 waves/CU (8/SIMD, 100% occupancy),
// single generation. VGPR target <=64: 8-group pinned load cluster
// (32 payload VGPRs), labels from LDS, rare-rescan reloads from L1.
// No atomics: per-block partial -> ws[blockIdx]; K2 reduces.
__global__ __launch_bounds__(512, 8) void minfonce_rows(
    const float* __restrict__ logits,
    const int*   __restrict__ labels,
    float*       __restrict__ ws)
{
    const int tid  = threadIdx.x;
    const int lane = tid & 63;
    const int wv   = tid >> 6;                    // 0..7
    const int half = wv & 1;                      // which half of the row
    const int row  = (blockIdx.x << 2) + (wv >> 1);

    __shared__ int4  slab[N_DIM / 4];             // 16 KB: all 4096 labels
    __shared__ float sS[8], sX[8], sM[8], sA[8];

    // ---- stage labels once (512 threads x 2 int4, coalesced) ----
    const int4* lp = reinterpret_cast<const int4*>(labels);
    slab[tid]       = lp[tid];
    slab[tid + 512] = lp[tid + 512];
    __syncthreads();
    const int li = reinterpret_cast<const int*>(slab)[row];

    const float4* rp = reinterpret_cast<const float4*>(logits + (size_t)row * N_DIM);
    const int     i0 = lane + (half << 9);        // this half's float4 index base

    // ---- issue this half-row as one pinned load cluster (8 x float4) ----
    const float4 u0 = rp[i0 +   0];
    const float4 u1 = rp[i0 +  64];
    const float4 u2 = rp[i0 + 128];
    const float4 u3 = rp[i0 + 192];
    const float4 u4 = rp[i0 + 256];
    const float4 u5 = rp[i0 + 320];
    const float4 u6 = rp[i0 + 384];
    const float4 u7 = rp[i0 + 448];
    const float  dv = logits[(size_t)row * N_DIM + row];   // bcast, L2-hot
    __builtin_amdgcn_sched_barrier(0);            // keep the cluster here

    // ---- consume in issue order (counted vmcnt overlap) ----
    float m8[8];
    float s_all = 0.f, s_mask = 0.f;
#define ACCG(G, U) do {                                                \
        const int4  lb = slab[i0 + 64 * (G)];                          \
        const float ex = __expf(SCALE * U.x);                          \
        const float ey = __expf(SCALE * U.y);                          \
        const float ez = __expf(SCALE * U.z);                          \
        const float ew = __expf(SCALE * U.w);                          \
        s_all  += (ex + ey) + (ez + ew);                               \
        s_mask += ((lb.x != li ? ex : 0.f) + (lb.y != li ? ey : 0.f))  \
                + ((lb.z != li ? ez : 0.f) + (lb.w != li ? ew : 0.f)); \
        m8[G] = fmaxf(fmaxf(ex, ey), fmaxf(ez, ew));                   \
    } while (0)
    ACCG(0, u0); ACCG(1, u1); ACCG(2, u2); ACCG(3, u3);
    ACCG(4, u4); ACCG(5, u5); ACCG(6, u6); ACCG(7, u7);
#undef ACCG

    float emax = m8[0];
#pragma unroll
    for (int g = 1; g < 8; ++g) emax = fmaxf(emax, m8[g]);

    // ---- intra-wave butterfly, then combine the row's two half-waves ----
#pragma unroll
    for (int off = 1; off < 64; off <<= 1) {
        s_all  += __shfl_xor(s_all, off);
        s_mask += __shfl_xor(s_mask, off);
        emax    = fmaxf(emax, __shfl_xor(emax, off));
    }
    if (lane == 0) { sS[wv] = s_all; sX[wv] = s_mask; sM[wv] = emax; }
    __syncthreads();                              // loads already consumed: cheap
    const int   w0    = wv & ~1;
    const float S     = sS[w0] + sS[w0 | 1];
    const float Smask = sX[w0] + sX[w0 | 1];
    const float Emax  = fmaxf(sM[w0], sM[w0 | 1]);
    const float invS  = 1.0f / S;
    const float tau   = 1e-3f * S;                // correction threshold (p > 1e-3)
    // 1 - p_max = (S - Emax)/S, cancellation-free; clamp guards S==Emax rounding.
    const float qmax  = fmaxf(S - Emax, S * 1e-12f) * invS;

    // ---- rare-correction scan: reload hit groups from L1, recompute exp
    //      (bit-identical, so the ev == Emax match is exact) ----
    float acc = 0.f;
#define FIX1(X, L) {                                                   \
        const float ev = __expf(SCALE * (X));                          \
        if (ev > tau && (L) != li) {                                   \
            const float p = ev * invS;                                 \
            const float q = (ev == Emax) ? qmax : (1.0f - p);          \
            acc += __logf(q) + p; } }
#define FIXG(G) if (m8[G] > tau) {                                     \
        const float4 t  = rp[i0 + 64 * (G)];                           \
        const int4   lb = slab[i0 + 64 * (G)];                         \
        FIX1(t.x, lb.x) FIX1(t.y, lb.y) FIX1(t.z, lb.z) FIX1(t.w, lb.w) }
    FIXG(0); FIXG(1); FIXG(2); FIXG(3);
    FIXG(4); FIXG(5); FIXG(6); FIXG(7);
#undef FIXG
#undef FIX1

    // ---- wave total; half-0 lane-0 adds per-row terms ----
#pragma unroll
    for (int off = 1; off < 64; off <<= 1)
        acc += __shfl_xor(acc, off);
    if (lane == 0) {
        float a = acc;
        if (half == 0)
            a += (SCALE * dv - __logf(S)) - Smask * invS;
        sA[wv] = a;
    }
    __syncthreads();
    if (tid == 0) {
        const float total = ((sA[0] + sA[1]) + (sA[2] + sA[3]))
                          + ((sA[4] + sA[5]) + (sA[6] + sA[7]));
        ws[blockIdx.x] = total;                   // no atomic
    }
}

// K2: sum the 1024 per-block partials, write the final scalar (overwrites
// poisoned d_out directly -- no memset needed).
__global__ __launch_bounds__(64) void minfonce_reduce(
    const float* __restrict__ ws,
    float*       __restrict__ out)
{
    const int lane = threadIdx.x;                 // one wave
    float a = 0.f;
#pragma unroll
    for (int i = 0; i < 16; ++i) a += ws[lane + 64 * i];
#pragma unroll
    for (int off = 1; off < 64; off <<= 1)
        a += __shfl_xor(a, off);
    if (lane == 0) out[0] = a * (1.0f / N_DIM);
}

extern "C" void kernel_launch(void* const* d_in, const int* in_sizes, int n_in,
                              void* d_out, int out_size, void* d_ws, size_t ws_size,
                              hipStream_t stream) {
    const float* logits = (const float*)d_in[0];
    const int*   labels = (const int*)d_in[1];
    float*       out    = (float*)d_out;
    float*       ws     = (float*)d_ws;

    minfonce_rows<<<N_DIM / 4, 512, 0, stream>>>(logits, labels, ws);
    minfonce_reduce<<<1, 64, 0, stream>>>(ws, out);
}